// Round 4
// baseline (74.240 us; speedup 1.0000x reference)
//
#include <hip/hip_runtime.h>

#define BB 32
#define HH 256
#define WW 256
#define CC 4
#define KH 5
#define KW 5
#define FF 8
#define HO (HH - KH + 1)   // 252
#define WO (WW - KW + 1)   // 252
#define PX 2               // output pixels per thread along x
#define PY 2               // output pixels per thread along y
#define NXT (WO / PX)      // 126
#define NYT (HO / PY)      // 126
#define NROW (PY + KH - 1) // 6 input rows per thread
#define NCOL (PX + KW - 1) // 6 input cols per thread

typedef _Float16 h2     __attribute__((ext_vector_type(2)));
typedef __fp16   fp16x2 __attribute__((ext_vector_type(2)));

static __device__ __forceinline__ h2 pkrtz(float a, float b) {
    fp16x2 r = __builtin_amdgcn_cvt_pkrtz(a, b);
    return __builtin_bit_cast(h2, r);
}

// --- Kernel A: pre-pack weights into f16 FILTER-pairs in d_ws. ---
// dword index i = tap*16 + c*4 + fp ; value = (k[tap,c,2fp], k[tap,c,2fp+1])
// 400 dwords = 1600 B.
__global__ void pack_kernel(const float* __restrict__ k, unsigned int* __restrict__ kp)
{
    int i = blockIdx.x * blockDim.x + threadIdx.x;
    if (i >= KH * KW * CC * FF / 2) return;   // 400
    int tap = i >> 4;
    int c   = (i >> 2) & 3;
    int fp  = i & 3;
    float a = k[(tap * CC + c) * FF + 2 * fp + 0];
    float b = k[(tap * CC + c) * FF + 2 * fp + 1];
    kp[i] = __builtin_bit_cast(unsigned int, pkrtz(a, b));
}

// --- Kernel B: 2x2 output tile per thread, packed f16 over filter pairs. ---
__global__ __launch_bounds__(256) void erosion2d_f16(
    const float* __restrict__ x,
    const h2* __restrict__ k2,        // d_ws, layout above
    float* __restrict__ out)
{
    const int total = BB * NYT * NXT;             // 508,032
    int tid = blockIdx.x * blockDim.x + threadIdx.x;
    if (tid >= total) return;

    int b   = tid / (NYT * NXT);
    int rem = tid - b * (NYT * NXT);
    int yt  = rem / NXT;
    int xt  = rem - yt * NXT;
    const int y0 = yt * PY;
    const int x0 = xt * PX;

    const float* xb = x + (((size_t)b * HH + y0) * WW + x0) * CC;

    h2 acc[PY][PX][FF / 2];
    const h2 big = { (_Float16)65504.0f, (_Float16)65504.0f };
#pragma unroll
    for (int py = 0; py < PY; ++py)
#pragma unroll
        for (int p = 0; p < PX; ++p)
#pragma unroll
            for (int fp = 0; fp < FF / 2; ++fp)
                acc[py][p][fp] = big;

#pragma unroll
    for (int r = 0; r < NROW; ++r) {
        // Load input row r (6 pixels) and broadcast each channel to an f16 pair.
        h2 xbc[NCOL][CC];
#pragma unroll
        for (int j = 0; j < NCOL; ++j) {
            const float4 px = *reinterpret_cast<const float4*>(xb + (r * WW + j) * CC);
            xbc[j][0] = pkrtz(px.x, px.x);
            xbc[j][1] = pkrtz(px.y, px.y);
            xbc[j][2] = pkrtz(px.z, px.z);
            xbc[j][3] = pkrtz(px.w, px.w);
        }
        // Apply row r to every output row it overlaps.
#pragma unroll
        for (int py = 0; py < PY; ++py) {
            const int dy = r - py;
            if (dy < 0 || dy >= KH) continue;
#pragma unroll
            for (int dx = 0; dx < KW; ++dx) {
                // Wave-uniform weight block: 16 dwords -> one s_load_dwordx16,
                // feeding 128 packed VALU ops below.
                const h2* kt = k2 + (dy * KW + dx) * (CC * FF / 2);
#pragma unroll
                for (int p = 0; p < PX; ++p) {
#pragma unroll
                    for (int c = 0; c < CC; ++c) {
                        const h2 xv = xbc[dx + p][c];
#pragma unroll
                        for (int fp = 0; fp < FF / 2; ++fp) {
                            h2 d = xv - kt[c * (FF / 2) + fp];
                            acc[py][p][fp] =
                                __builtin_elementwise_min(acc[py][p][fp], d);
                        }
                    }
                }
            }
        }
    }

    // Epilogue: f16 -> f32, 2x float4 store per output pixel.
#pragma unroll
    for (int py = 0; py < PY; ++py) {
#pragma unroll
        for (int p = 0; p < PX; ++p) {
            float* op = out + (((size_t)b * HO + (y0 + py)) * WO + (x0 + p)) * FF;
            float4 o0 = make_float4((float)acc[py][p][0][0], (float)acc[py][p][0][1],
                                    (float)acc[py][p][1][0], (float)acc[py][p][1][1]);
            float4 o1 = make_float4((float)acc[py][p][2][0], (float)acc[py][p][2][1],
                                    (float)acc[py][p][3][0], (float)acc[py][p][3][1]);
            *reinterpret_cast<float4*>(op)     = o0;
            *reinterpret_cast<float4*>(op + 4) = o1;
        }
    }
}

extern "C" void kernel_launch(void* const* d_in, const int* in_sizes, int n_in,
                              void* d_out, int out_size, void* d_ws, size_t ws_size,
                              hipStream_t stream) {
    const float* x = (const float*)d_in[0];
    const float* k = (const float*)d_in[1];
    float* out = (float*)d_out;

    pack_kernel<<<2, 256, 0, stream>>>(k, (unsigned int*)d_ws);

    const int total = BB * NYT * NXT;                // 508,032 threads
    const int block = 256;
    const int grid  = (total + block - 1) / block;   // 1985 blocks
    erosion2d_f16<<<grid, block, 0, stream>>>(x, (const h2*)d_ws, out);
}

// Round 5
// 70.851 us; speedup vs baseline: 1.0478x; 1.0478x over previous
//
#include <hip/hip_runtime.h>

#define BB 32
#define HH 256
#define WW 256
#define CC 4
#define KH 5
#define KW 5
#define FF 8
#define HO (HH - KH + 1)   // 252
#define WO (WW - KW + 1)   // 252
#define PX 4               // output pixels per thread along x; WO % PX == 0
#define NXT (WO / PX)      // 63
#define NCOL (PX + KW - 1) // 8 input columns per thread

typedef _Float16 h2     __attribute__((ext_vector_type(2)));
typedef __fp16   fp16x2 __attribute__((ext_vector_type(2)));

static __device__ __forceinline__ h2 pkrtz(float a, float b) {
    fp16x2 r = __builtin_amdgcn_cvt_pkrtz(a, b);
    return __builtin_bit_cast(h2, r);
}

// --- Kernel A: pre-pack weights into f16 CHANNEL-pairs in d_ws. ---
// dword index i = tap*16 + f*2 + pair; value = (k[tap, 2p, f], k[tap, 2p+1, f]).
// 400 dwords = 1600 B.
__global__ void pack_kernel(const float* __restrict__ k, unsigned int* __restrict__ kp)
{
    int i = blockIdx.x * blockDim.x + threadIdx.x;
    if (i >= KH * KW * FF * 2) return;        // 400
    int t = i >> 4;          // tap = dy*KW+dx
    int r = i & 15;
    int f = r >> 1;
    int p = r & 1;           // channel pair
    float a = k[(t * CC + 2 * p + 0) * FF + f];
    float b = k[(t * CC + 2 * p + 1) * FF + f];
    kp[i] = __builtin_bit_cast(unsigned int, pkrtz(a, b));
}

// --- Kernel B: 1x4 output strip per thread; load-all-then-compute. ---
// __launch_bounds__(256, 3): min 3 waves/EU -> VGPR cap ~168; tells the
// scheduler NOT to minimize registers (R3/R4 collapsed to 24-32 VGPR and
// serialized load->use). 40 loads in flight per thread = ILP latency hiding.
__global__ __launch_bounds__(256, 3) void erosion2d_f16(
    const float* __restrict__ x,
    const h2* __restrict__ k2,        // d_ws, layout above
    float* __restrict__ out)
{
    const int total = BB * HO * NXT;             // 508,032
    int tid = blockIdx.x * blockDim.x + threadIdx.x;
    if (tid >= total) return;

    int b   = tid / (HO * NXT);
    int rem = tid - b * (HO * NXT);
    int y   = rem / NXT;
    int xt  = rem - y * NXT;
    const int x0 = xt * PX;

    const float* xb = x + (((size_t)b * HH + y) * WW + x0) * CC;

    // Phase 1: load all 5x8 input pixels, convert to f16 channel pairs.
    // 80 dwords, statically indexed -> stays in VGPRs.
    h2 pc[KH][NCOL][2];
#pragma unroll
    for (int r = 0; r < KH; ++r) {
#pragma unroll
        for (int j = 0; j < NCOL; ++j) {
            const float4 px = *reinterpret_cast<const float4*>(xb + (r * WW + j) * CC);
            pc[r][j][0] = pkrtz(px.x, px.y);
            pc[r][j][1] = pkrtz(px.z, px.w);
        }
    }

    h2 acc[PX][FF];
    const h2 big = { (_Float16)65504.0f, (_Float16)65504.0f };
#pragma unroll
    for (int p = 0; p < PX; ++p)
#pragma unroll
        for (int f = 0; f < FF; ++f)
            acc[p][f] = big;

    // Phase 2: pure-VALU core. Per tap: one s_load_dwordx16 of weights
    // feeds 4*8*4 = 128 packed ops across 32 independent min-chains.
#pragma unroll
    for (int dy = 0; dy < KH; ++dy) {
#pragma unroll
        for (int dx = 0; dx < KW; ++dx) {
            const h2* kt = k2 + (dy * KW + dx) * (FF * 2);
#pragma unroll
            for (int p = 0; p < PX; ++p) {
                const h2 c01 = pc[dy][dx + p][0];
                const h2 c23 = pc[dy][dx + p][1];
#pragma unroll
                for (int f = 0; f < FF; ++f) {
                    h2 d01 = c01 - kt[f * 2 + 0];
                    h2 d23 = c23 - kt[f * 2 + 1];
                    acc[p][f] = __builtin_elementwise_min(
                        acc[p][f], __builtin_elementwise_min(d01, d23));
                }
            }
        }
    }

    // Epilogue: horizontal min over the channel pair, f16 -> f32, store
    // 4 pixels * 32 B = 128 contiguous bytes per thread.
#pragma unroll
    for (int p = 0; p < PX; ++p) {
        float r[FF];
#pragma unroll
        for (int f = 0; f < FF; ++f)
            r[f] = fminf((float)acc[p][f][0], (float)acc[p][f][1]);
        float* op = out + (((size_t)b * HO + y) * WO + (x0 + p)) * FF;
        *reinterpret_cast<float4*>(op)     = make_float4(r[0], r[1], r[2], r[3]);
        *reinterpret_cast<float4*>(op + 4) = make_float4(r[4], r[5], r[6], r[7]);
    }
}

extern "C" void kernel_launch(void* const* d_in, const int* in_sizes, int n_in,
                              void* d_out, int out_size, void* d_ws, size_t ws_size,
                              hipStream_t stream) {
    const float* x = (const float*)d_in[0];
    const float* k = (const float*)d_in[1];
    float* out = (float*)d_out;

    pack_kernel<<<2, 256, 0, stream>>>(k, (unsigned int*)d_ws);

    const int total = BB * HO * NXT;                 // 508,032 threads
    const int block = 256;
    const int grid  = (total + block - 1) / block;   // 1985 blocks
    erosion2d_f16<<<grid, block, 0, stream>>>(x, (const h2*)d_ws, out);
}

// Round 6
// 61.381 us; speedup vs baseline: 1.2095x; 1.1543x over previous
//
#include <hip/hip_runtime.h>

#define BB 32
#define HH 256
#define WW 256
#define CC 4
#define KH 5
#define KW 5
#define FF 8
#define HO (HH - KH + 1)   // 252
#define WO (WW - KW + 1)   // 252
#define PX 2               // output pixels per thread along x; WO % PX == 0
#define NXT (WO / PX)      // 126
#define NCOL (PX + KW - 1) // 6 input columns per thread

typedef _Float16 h2     __attribute__((ext_vector_type(2)));
typedef __fp16   fp16x2 __attribute__((ext_vector_type(2)));
typedef unsigned int u32x4 __attribute__((ext_vector_type(4)));

static __device__ __forceinline__ h2 pkrtz(float a, float b) {
    fp16x2 r = __builtin_amdgcn_cvt_pkrtz(a, b);
    return __builtin_bit_cast(h2, r);
}
static __device__ __forceinline__ h2 ash2(unsigned int u) {
    return __builtin_bit_cast(h2, u);
}

// Single fused kernel: per-block weight pack into LDS, then pk-f16 erosion.
// LDS layout (dword i = tap*16 + f*2 + pair): pk(k[tap,2p,f], k[tap,2p+1,f]).
__global__ __launch_bounds__(256) void erosion2d_f16(
    const float* __restrict__ x,
    const float* __restrict__ k,
    float* __restrict__ out)
{
    __shared__ unsigned int lw[KH * KW * 16];   // 400 dwords = 1.6 KB

    // ---- weight pack (replaces the separate pack kernel: no extra graph
    // node, no s_load dependency chains in the main loop) ----
    for (int i = threadIdx.x; i < KH * KW * 16; i += 256) {
        int t = i >> 4;          // tap
        int r = i & 15;
        int f = r >> 1;
        int p = r & 1;           // channel pair
        float a = k[(t * CC + 2 * p + 0) * FF + f];
        float b = k[(t * CC + 2 * p + 1) * FF + f];
        lw[i] = __builtin_bit_cast(unsigned int, pkrtz(a, b));
    }
    __syncthreads();

    const int total = BB * HO * NXT;             // 1,016,064 (= 3969 * 256)
    int tid = blockIdx.x * blockDim.x + threadIdx.x;
    if (tid >= total) return;

    int b   = tid / (HO * NXT);
    int rem = tid - b * (HO * NXT);
    int y   = rem / NXT;
    int xt  = rem - y * NXT;
    const int x0 = xt * PX;

    const float* xb = x + (((size_t)b * HH + y) * WW + x0) * CC;

    h2 acc[PX][FF];
    const h2 big = { (_Float16)65504.0f, (_Float16)65504.0f };
#pragma unroll
    for (int p = 0; p < PX; ++p)
#pragma unroll
        for (int f = 0; f < FF; ++f)
            acc[p][f] = big;

    // ---- row software-pipeline: raw holds row r+1 loads in flight while
    // row r computes from converted registers ----
    float4 raw[NCOL];
    h2 cur[NCOL][2];

#pragma unroll
    for (int j = 0; j < NCOL; ++j)
        raw[j] = *reinterpret_cast<const float4*>(xb + j * CC);

#pragma unroll
    for (int r = 0; r < KH; ++r) {
        // Convert the row we just finished waiting on.
#pragma unroll
        for (int j = 0; j < NCOL; ++j) {
            cur[j][0] = pkrtz(raw[j].x, raw[j].y);
            cur[j][1] = pkrtz(raw[j].z, raw[j].w);
        }
        // Issue next row's loads; consumed only after this row's compute.
        if (r + 1 < KH) {
#pragma unroll
            for (int j = 0; j < NCOL; ++j)
                raw[j] = *reinterpret_cast<const float4*>(xb + ((r + 1) * WW + j) * CC);
        }
        // Compute row r: 5 taps, each = 4 broadcast ds_read_b128 + 64 pk ops.
#pragma unroll
        for (int dx = 0; dx < KW; ++dx) {
            const u32x4* q = reinterpret_cast<const u32x4*>(&lw[(r * KW + dx) * 16]);
            u32x4 q0 = q[0], q1 = q[1], q2 = q[2], q3 = q[3];
            h2 w01[FF], w23[FF];
            w01[0] = ash2(q0[0]); w23[0] = ash2(q0[1]);
            w01[1] = ash2(q0[2]); w23[1] = ash2(q0[3]);
            w01[2] = ash2(q1[0]); w23[2] = ash2(q1[1]);
            w01[3] = ash2(q1[2]); w23[3] = ash2(q1[3]);
            w01[4] = ash2(q2[0]); w23[4] = ash2(q2[1]);
            w01[5] = ash2(q2[2]); w23[5] = ash2(q2[3]);
            w01[6] = ash2(q3[0]); w23[6] = ash2(q3[1]);
            w01[7] = ash2(q3[2]); w23[7] = ash2(q3[3]);
#pragma unroll
            for (int p = 0; p < PX; ++p) {
                const h2 c01 = cur[dx + p][0];
                const h2 c23 = cur[dx + p][1];
#pragma unroll
                for (int f = 0; f < FF; ++f) {
                    h2 d01 = c01 - w01[f];
                    h2 d23 = c23 - w23[f];
                    acc[p][f] = __builtin_elementwise_min(
                        acc[p][f], __builtin_elementwise_min(d01, d23));
                }
            }
        }
    }

    // ---- epilogue: horizontal min over the channel pair, f16->f32, store
    // 64 contiguous bytes per thread ----
#pragma unroll
    for (int p = 0; p < PX; ++p) {
        float rr[FF];
#pragma unroll
        for (int f = 0; f < FF; ++f) {
            _Float16 m = __builtin_elementwise_min(acc[p][f][0], acc[p][f][1]);
            rr[f] = (float)m;
        }
        float* op = out + ((size_t)tid * PX + p) * FF;
        *reinterpret_cast<float4*>(op)     = make_float4(rr[0], rr[1], rr[2], rr[3]);
        *reinterpret_cast<float4*>(op + 4) = make_float4(rr[4], rr[5], rr[6], rr[7]);
    }
}

extern "C" void kernel_launch(void* const* d_in, const int* in_sizes, int n_in,
                              void* d_out, int out_size, void* d_ws, size_t ws_size,
                              hipStream_t stream) {
    const float* x = (const float*)d_in[0];
    const float* k = (const float*)d_in[1];
    float* out = (float*)d_out;

    const int total = BB * HO * NXT;                 // 1,016,064 threads
    const int block = 256;
    const int grid  = (total + block - 1) / block;   // 3969 blocks
    erosion2d_f16<<<grid, block, 0, stream>>>(x, k, out);
}